// Round 7
// baseline (84.834 us; speedup 1.0000x reference)
//
#include <hip/hip_runtime.h>

typedef __bf16 bf16x8 __attribute__((ext_vector_type(8)));
typedef float f32x4 __attribute__((ext_vector_type(4)));

// Problem constants: B=4, Cin=64, Cout=64, H=W=128, K=3, PAD=1, KK=9

// ------- Kernel 1: x NCHW f32 -> xt NHWC bf16 (1024 blks) + weight prep (216 blks) -------
__global__ __launch_bounds__(256) void k_xtprep(const float* __restrict__ x,
                                                const float* __restrict__ wt,
                                                const float* __restrict__ ow,
                                                __bf16* __restrict__ xt,
                                                __bf16* __restrict__ wb,
                                                __bf16* __restrict__ owb) {
  __shared__ float tile[64 * 65];
  int blk = blockIdx.x;
  int t = threadIdx.x;
  if (blk < 1024) {
    int b = blk >> 8;
    int y = (blk >> 1) & 127;
    int w0 = (blk & 1) * 64;
    const float* xp = x + ((size_t)(b * 64) * 128 + y) * 128 + w0;
    // load 64c x 64w as float4
#pragma unroll
    for (int it = 0; it < 4; ++it) {
      int idx = it * 256 + t;        // 1024 float4 tasks
      int c = idx >> 4, q = idx & 15;
      float4 v = *(const float4*)(xp + (size_t)c * 16384 + q * 4);
      float* tp = &tile[c * 65 + q * 4];
      tp[0] = v.x; tp[1] = v.y; tp[2] = v.z; tp[3] = v.w;
    }
    __syncthreads();
    // write transposed bf16x8: tasks (w, c8)
#pragma unroll
    for (int it = 0; it < 2; ++it) {
      int idx = it * 256 + t;        // 512 tasks
      int w = idx >> 3, c8 = idx & 7;
      bf16x8 o;
#pragma unroll
      for (int j = 0; j < 8; ++j) o[j] = (__bf16)tile[(c8 * 8 + j) * 65 + w];
      *(bf16x8*)&xt[(((size_t)b * 128 + y) * 128 + w0 + w) * 64 + c8 * 8] = o;
    }
  } else {
    int i = (blk - 1024) * 256 + t;
    if (i < 36864) {
      int k = i >> 12, rem = i & 4095, o = rem >> 6, c = rem & 63;
      wb[i] = (__bf16)wt[(o * 64 + c) * 9 + k];
    } else if (i < 36864 + 18432) {
      int j = i - 36864;
      int k = j >> 11, rem = j & 2047, o = rem >> 6, c = rem & 63;
      float v = (o < 18) ? ow[(o * 64 + c) * 9 + k] : 0.0f;
      owb[j] = (__bf16)v;
    }
  }
}

// ---------------- Kernel 2: offset conv -> offs (global f32) ----------------
// grid 2048 = (4 wtiles of 32px) x (128 h) x (4 b); 256 threads (4 waves)
__global__ __launch_bounds__(256, 8) void k_off(
    const __bf16* __restrict__ xt, const __bf16* __restrict__ owb,
    const float* __restrict__ ob, float* __restrict__ offs) {
  __shared__ __bf16 Xs[3 * 34 * 72];  // 14688 B

  int t = threadIdx.x;
  int w0 = (blockIdx.x & 3) * 32;
  int h = (blockIdx.x >> 2) & 127;
  int b = blockIdx.x >> 9;

  int lane = t & 63, wid = t >> 6;
  int row = lane & 15, quad = lane >> 4;
  const __bf16* xb = xt + (size_t)b * 128 * 128 * 64;

  // Stage0: rows h-1..h+1, pixels w0-1..w0+32 (34), all 64c; zero-pad OOB
#pragma unroll
  for (int it = 0; it < 4; ++it) {
    int idx8 = it * 256 + t;  // 816 chunks of bf16x8
    if (idx8 < 816) {
      int c8 = idx8 & 7;
      int jr = idx8 >> 3;  // 0..101
      int jj = jr % 34;
      int ki = jr / 34;
      int gy = h - 1 + ki;
      int gx = w0 - 1 + jj;
      bf16x8 v = {};
      if (((unsigned)gy < 128u) & ((unsigned)gx < 128u))
        v = *(const bf16x8*)(xb + ((size_t)gy * 128 + gx) * 64 + c8 * 8);
      *(bf16x8*)&Xs[(ki * 34 + jj) * 72 + c8 * 8] = v;
    }
  }
  __syncthreads();

  // offset MFMA: M=18pad32 (2 halves), N=32px (2 halves), K=576
  int woA = (wid >> 1) * 16;
  int wpA = (wid & 1) * 16;
  f32x4 accA = f32x4{0.f, 0.f, 0.f, 0.f};
#pragma unroll
  for (int k = 0; k < 9; ++k) {
    int ki = k / 3, kj = k % 3;
    const __bf16* ap = owb + k * 2048 + (woA + row) * 64 + quad * 8;
    bf16x8 afr0 = *(const bf16x8*)(ap);
    bf16x8 afr1 = *(const bf16x8*)(ap + 32);
    int j = wpA + row + kj;  // 0..33
    const __bf16* lp = &Xs[(ki * 34 + j) * 72 + quad * 8];
    bf16x8 b0 = *(const bf16x8*)(lp);
    bf16x8 b1 = *(const bf16x8*)(lp + 32);
    accA = __builtin_amdgcn_mfma_f32_16x16x32_bf16(afr0, b0, accA, 0, 0, 0);
    accA = __builtin_amdgcn_mfma_f32_16x16x32_bf16(afr1, b1, accA, 0, 0, 0);
  }
  // epilogue: col=lane&15 (px), row=quad*4+r (co)
  int qr = quad * 4;
#pragma unroll
  for (int r = 0; r < 4; ++r) {
    int co = woA + qr + r;
    if (co < 18)
      offs[(((size_t)b * 18 + co) * 128 + h) * 128 + w0 + wpA + row] =
          accA[r] + ob[co];
  }
}

// ---------------- Kernel 3: main GEMM with pipelined sampling ----------------
// grid 2048 = (4 wtiles of 32px) x (128 h) x (4 b); 256 threads (4 waves)
// SP precompute (per px-tap params) -> LDS once; then 9 taps: issue gathers(k+1),
// MFMA(k), interp+store(k+1), 1 barrier. Double-buffered S.
__global__ __launch_bounds__(256, 6) void k_main(
    const __bf16* __restrict__ xt, const __bf16* __restrict__ wb,
    const float* __restrict__ offs, const float* __restrict__ bias,
    float* __restrict__ out) {
  __shared__ float4 SPw[288];          // 4608 B: w00,w01,w10,w11
  __shared__ int4 SPb[288];            // 4608 B: base, dxo, dyo, -
  __shared__ __bf16 S[2][32 * 72];     // 2 x 4608 B

  int t = threadIdx.x;
  int w0 = (blockIdx.x & 3) * 32;
  int h = (blockIdx.x >> 2) & 127;
  int b = blockIdx.x >> 9;

  int lane = t & 63, wid = t >> 6;
  int row = lane & 15, quad = lane >> 4;
  const __bf16* xb = xt + (size_t)b * 128 * 128 * 64;

  // ---- SP precompute: 288 tasks = 9 taps x 32 px ----
  for (int j = t; j < 288; j += 256) {
    int tap = j >> 5, px = j & 31;
    int w = w0 + px;
    float dy = offs[(((size_t)b * 18 + 2 * tap) * 128 + h) * 128 + w];
    float dx = offs[(((size_t)b * 18 + 2 * tap + 1) * 128 + h) * 128 + w];
    float py = dy + (float)(h + tap / 3 - 1);
    float pxf = dx + (float)(w + tap % 3 - 1);
    float fy = floorf(py), fx = floorf(pxf);
    float ly = py - fy, lx = pxf - fx;
    int y0 = (int)fy, x0 = (int)fx;
    int y1 = y0 + 1, x1 = x0 + 1;
    bool vy0 = (unsigned)y0 < 128u, vy1 = (unsigned)y1 < 128u;
    bool vx0 = (unsigned)x0 < 128u, vx1 = (unsigned)x1 < 128u;
    float4 ww;
    ww.x = (vy0 && vx0) ? (1.f - ly) * (1.f - lx) : 0.f;
    ww.y = (vy0 && vx1) ? (1.f - ly) * lx : 0.f;
    ww.z = (vy1 && vx0) ? ly * (1.f - lx) : 0.f;
    ww.w = (vy1 && vx1) ? ly * lx : 0.f;
    int yc0 = min(max(y0, 0), 127), yc1 = min(max(y1, 0), 127);
    int xc0 = min(max(x0, 0), 127), xc1 = min(max(x1, 0), 127);
    SPw[j] = ww;
    SPb[j] = int4{(yc0 * 128 + xc0) * 64, (xc1 - xc0) * 64,
                  (yc1 - yc0) * 8192, 0};
  }
  __syncthreads();

  // sampling role: px = t>>3 (0..31), cg = t&7 (8 channels each)
  int spx = t >> 3, scg = t & 7;
  // MFMA role: wave (wid>>1) -> o-half (32), (wid&1) -> px-half (16)
  int woB = (wid >> 1) * 32, wpB = (wid & 1) * 16;

  f32x4 acc[2];
  acc[0] = f32x4{0.f, 0.f, 0.f, 0.f};
  acc[1] = f32x4{0.f, 0.f, 0.f, 0.f};

  // prologue: tap 0 -> S[0]
  {
    float4 ww = SPw[spx];
    int4 bb = SPb[spx];
    const __bf16* p = xb + bb.x + scg * 8;
    bf16x8 ga = *(const bf16x8*)(p);
    bf16x8 gb = *(const bf16x8*)(p + bb.y);
    bf16x8 gc = *(const bf16x8*)(p + bb.z);
    bf16x8 gd = *(const bf16x8*)(p + bb.y + bb.z);
    bf16x8 o;
#pragma unroll
    for (int j = 0; j < 8; ++j)
      o[j] = (__bf16)(ww.x * (float)ga[j] + ww.y * (float)gb[j] +
                      ww.z * (float)gc[j] + ww.w * (float)gd[j]);
    *(bf16x8*)&S[0][spx * 72 + scg * 8] = o;
  }
  __syncthreads();

#pragma unroll
  for (int k = 0; k < 9; ++k) {
    bf16x8 ga, gb, gc, gd;
    float4 ww;
    if (k < 8) {  // issue next tap's gathers before MFMA
      int j = (k + 1) * 32 + spx;
      ww = SPw[j];
      int4 bb = SPb[j];
      const __bf16* p = xb + bb.x + scg * 8;
      ga = *(const bf16x8*)(p);
      gb = *(const bf16x8*)(p + bb.y);
      gc = *(const bf16x8*)(p + bb.z);
      gd = *(const bf16x8*)(p + bb.y + bb.z);
    }
    // MFMA tap k from S[k&1]; A-frags from L1/L2-hot wb
    {
      const __bf16* wk = wb + k * 4096;
      const __bf16* Sb = S[k & 1];
#pragma unroll
      for (int ks = 0; ks < 2; ++ks) {
        int c0 = ks * 32 + quad * 8;
        bf16x8 bfr = *(const bf16x8*)&Sb[(wpB + row) * 72 + c0];
#pragma unroll
        for (int mi = 0; mi < 2; ++mi) {
          bf16x8 afr = *(const bf16x8*)(wk + (woB + mi * 16 + row) * 64 + c0);
          acc[mi] = __builtin_amdgcn_mfma_f32_16x16x32_bf16(afr, bfr, acc[mi],
                                                            0, 0, 0);
        }
      }
    }
    if (k < 8) {  // interp + store to the other buffer
      bf16x8 o;
#pragma unroll
      for (int j = 0; j < 8; ++j)
        o[j] = (__bf16)(ww.x * (float)ga[j] + ww.y * (float)gb[j] +
                        ww.z * (float)gc[j] + ww.w * (float)gd[j]);
      *(bf16x8*)&S[(k + 1) & 1][spx * 72 + scg * 8] = o;
    }
    __syncthreads();
  }
  // epilogue: col=lane&15 (px), row=quad*4+r (o)
  {
    int qr = quad * 4;
#pragma unroll
    for (int mi = 0; mi < 2; ++mi) {
#pragma unroll
      for (int r = 0; r < 4; ++r) {
        int o = woB + mi * 16 + qr + r;
        out[(((size_t)b * 64 + o) * 128 + h) * 128 + w0 + wpB + row] =
            acc[mi][r] + bias[o];
      }
    }
  }
}

extern "C" void kernel_launch(void* const* d_in, const int* in_sizes, int n_in,
                              void* d_out, int out_size, void* d_ws,
                              size_t ws_size, hipStream_t stream) {
  const float* x = (const float*)d_in[0];       // (4,64,128,128)
  const float* ow = (const float*)d_in[1];      // (18,64,3,3)
  const float* ob = (const float*)d_in[2];      // (18,)
  const float* wt = (const float*)d_in[3];      // (64,64,3,3)
  const float* bias = (const float*)d_in[4];    // (64,)
  float* out = (float*)d_out;                   // (4,64,128,128)

  char* ws = (char*)d_ws;
  __bf16* xt = (__bf16*)ws;                      // 8,388,608 B
  __bf16* wb = (__bf16*)(ws + 8388608);          // 73,728 B
  __bf16* owb = (__bf16*)(ws + 8388608 + 73728); // 36,864 B
  float* offs = (float*)(ws + 8388608 + 73728 + 36864);  // 4,718,592 B

  k_xtprep<<<1240, 256, 0, stream>>>(x, wt, ow, xt, wb, owb);
  k_off<<<2048, 256, 0, stream>>>(xt, owb, ob, offs);
  k_main<<<2048, 256, 0, stream>>>(xt, wb, offs, bias, out);
}